// Round 5
// baseline (673.645 us; speedup 1.0000x reference)
//
#include <hip/hip_runtime.h>
#include <hip/hip_bf16.h>
#include <math.h>

typedef __bf16 bf16;
typedef __bf16 bf16x8 __attribute__((ext_vector_type(8)));
typedef __bf16 bf16x4 __attribute__((ext_vector_type(4)));
typedef float  f32x4  __attribute__((ext_vector_type(4)));

#define HRES 128
#define WRES 128
#define CDIM 256
#define NHEADS 8
#define HD 32
#define NWIN 64      // tokens per window
#define LTOK 16384   // tokens per image
#define BATCH 4
#define TOK_TOTAL 65536
#define HIDDEN 1024

__device__ __forceinline__ float gelu_exact(float v) {
    return 0.5f * v * (1.0f + erff(v * 0.70710678118654752f));
}

// async global->LDS, 16 bytes per lane (dest must be wave-uniform base + lane*16)
__device__ __forceinline__ void gld16(const bf16* g, bf16* l) {
    __builtin_amdgcn_global_load_lds(
        (const __attribute__((address_space(1))) unsigned int*)g,
        (__attribute__((address_space(3))) unsigned int*)l, 16, 0, 0);
}

// ---------------- prep kernels ----------------

// Combined QKV weight transpose -> Bt [768][256] bf16, bias_qkv [768] f32
__global__ void prep_qkvw(const float* __restrict__ wq, const float* __restrict__ bq,
                          const float* __restrict__ wkv, const float* __restrict__ bkv,
                          bf16* __restrict__ bt, float* __restrict__ bias) {
    int idx = blockIdx.x * 256 + threadIdx.x;   // 768*256
    int c = idx >> 8, k = idx & 255;
    float v = (c < 256) ? wq[k * 256 + c] : wkv[k * 512 + (c - 256)];
    bt[idx] = (bf16)v;
    if (k == 0) bias[c] = (c < 256) ? bq[c] : bkv[c - 256];
}

// generic transpose to bf16: wt[n*K+k] = w[k*N+n]
__global__ void prep_wt(const float* __restrict__ w, bf16* __restrict__ wt, int K, int N) {
    int idx = blockIdx.x * 256 + threadIdx.x;
    if (idx >= K * N) return;
    int n = idx / K, k = idx - n * K;
    wt[idx] = (bf16)w[(size_t)k * N + n];
}

// rel-pos bias table: btab[h][n][m]
__global__ void prep_btab(const float* __restrict__ rpb, float* __restrict__ btab) {
    int idx = blockIdx.x * 256 + threadIdx.x;   // 8*64*64 = 32768
    int h = idx >> 12;
    int n = (idx >> 6) & 63;
    int m = idx & 63;
    int i1 = n >> 3, j1 = n & 7, i2 = m >> 3, j2 = m & 7;
    int rel = (i1 - i2 + 7) * 15 + (j1 - j2 + 7);
    btab[idx] = rpb[rel * NHEADS + h];
}

// ---------------- LN kernels ----------------

// LN1 + cyclic shift(-4,-4) + window partition; out xw bf16 [65536][256] in window-token order
__global__ void ln1_winpart(const float* __restrict__ x, const float* __restrict__ g,
                            const float* __restrict__ be, bf16* __restrict__ xw) {
    int wv = (blockIdx.x * blockDim.x + threadIdx.x) >> 6;   // token in window order
    int lane = threadIdx.x & 63;
    int bw = wv >> 6, n = wv & 63;
    int b = bw >> 8, w = bw & 255;
    int wh = w >> 4, ww = w & 15;
    int i = n >> 3, j = n & 7;
    int ph = (wh * 8 + i + 4) & 127, pw = (ww * 8 + j + 4) & 127;
    const float* row = x + ((size_t)(b * LTOK + ph * 128 + pw)) * CDIM;
    float4 v = *(const float4*)(row + lane * 4);
    float s = v.x + v.y + v.z + v.w;
    float ss = v.x * v.x + v.y * v.y + v.z * v.z + v.w * v.w;
    #pragma unroll
    for (int m = 1; m < 64; m <<= 1) { s += __shfl_xor(s, m); ss += __shfl_xor(ss, m); }
    float mu = s * (1.0f / 256.0f);
    float var = ss * (1.0f / 256.0f) - mu * mu;
    float inv = rsqrtf(var + 1e-5f);
    int c0 = lane * 4;
    bf16x4 o;
    o[0] = (bf16)((v.x - mu) * inv * g[c0 + 0] + be[c0 + 0]);
    o[1] = (bf16)((v.y - mu) * inv * g[c0 + 1] + be[c0 + 1]);
    o[2] = (bf16)((v.z - mu) * inv * g[c0 + 2] + be[c0 + 2]);
    o[3] = (bf16)((v.w - mu) * inv * g[c0 + 3] + be[c0 + 3]);
    *(bf16x4*)(xw + (size_t)wv * CDIM + c0) = o;
}

// LN2 (identity token order): x2 f32 -> yln bf16
__global__ void ln2_kernel(const float* __restrict__ x2, const float* __restrict__ g,
                           const float* __restrict__ be, bf16* __restrict__ y) {
    int t = (blockIdx.x * blockDim.x + threadIdx.x) >> 6;
    int lane = threadIdx.x & 63;
    const float* row = x2 + (size_t)t * CDIM;
    float4 v = *(const float4*)(row + lane * 4);
    float s = v.x + v.y + v.z + v.w;
    float ss = v.x * v.x + v.y * v.y + v.z * v.z + v.w * v.w;
    #pragma unroll
    for (int m = 1; m < 64; m <<= 1) { s += __shfl_xor(s, m); ss += __shfl_xor(ss, m); }
    float mu = s * (1.0f / 256.0f);
    float var = ss * (1.0f / 256.0f) - mu * mu;
    float inv = rsqrtf(var + 1e-5f);
    int c0 = lane * 4;
    bf16x4 o;
    o[0] = (bf16)((v.x - mu) * inv * g[c0 + 0] + be[c0 + 0]);
    o[1] = (bf16)((v.y - mu) * inv * g[c0 + 1] + be[c0 + 1]);
    o[2] = (bf16)((v.z - mu) * inv * g[c0 + 2] + be[c0 + 2]);
    o[3] = (bf16)((v.w - mu) * inv * g[c0 + 3] + be[c0 + 3]);
    *(bf16x4*)(y + (size_t)t * CDIM + c0) = o;
}

// ---------------- generic MFMA GEMM (A[M,K] bf16 row-major, Bt[N,K] bf16 row-major) ----------------
// m97-structure: linear LDS tiles, global_load_lds dwordx4 staging, 2-barrier loop.
// EPI: 0=QKV scatter, 1=proj(win_rev+roll+residual->f32), 2=MLP1(gelu->bf16), 3=MLP2(+res in-place f32)
template <int EPI>
__global__ __launch_bounds__(256) void gemm_bt(
    const bf16* __restrict__ A, const bf16* __restrict__ Bt,
    const float* __restrict__ bias, int M, int N, int K, int row0,
    bf16* __restrict__ outb, float* __restrict__ outf, const float* __restrict__ add_f32,
    bf16* __restrict__ qb, bf16* __restrict__ kb, bf16* __restrict__ vtb)
{
    __shared__ bf16 As[128][64];
    __shared__ bf16 Bs[128][64];
    int tid = threadIdx.x;
    int lane = tid & 63;
    int wid = tid >> 6;
    int bm = blockIdx.x * 128, bn = blockIdx.y * 128;
    int wm = (wid >> 1) * 64, wn = (wid & 1) * 64;
    int l15 = lane & 15, l4 = lane >> 4;
    f32x4 acc[4][4] = {};

    const bf16* Abase = A + (size_t)bm * K;
    const bf16* Bbase = Bt + (size_t)bn * K;

    for (int k0 = 0; k0 < K; k0 += 64) {
        #pragma unroll
        for (int it = 0; it < 4; ++it) {
            int e = (it * 256 + tid) * 8;          // element index within 128x64 tile
            int r = e >> 6, kk = e & 63;           // LDS byte off = e*2 = it*4096 + wid*1024 + lane*16
            gld16(Abase + (size_t)r * K + k0 + kk, &As[0][0] + e);
            gld16(Bbase + (size_t)r * K + k0 + kk, &Bs[0][0] + e);
        }
        __syncthreads();                           // drains vmcnt before compute
        #pragma unroll
        for (int kh = 0; kh < 2; ++kh) {
            bf16x8 af[4], bfr[4];
            #pragma unroll
            for (int mf = 0; mf < 4; ++mf) af[mf]  = *(const bf16x8*)(&As[wm + mf * 16 + l15][kh * 32 + 8 * l4]);
            #pragma unroll
            for (int nf = 0; nf < 4; ++nf) bfr[nf] = *(const bf16x8*)(&Bs[wn + nf * 16 + l15][kh * 32 + 8 * l4]);
            #pragma unroll
            for (int mf = 0; mf < 4; ++mf)
                #pragma unroll
                for (int nf = 0; nf < 4; ++nf)
                    acc[mf][nf] = __builtin_amdgcn_mfma_f32_16x16x32_bf16(af[mf], bfr[nf], acc[mf][nf], 0, 0, 0);
        }
        __syncthreads();
    }

    #pragma unroll
    for (int mf = 0; mf < 4; ++mf)
      #pragma unroll
      for (int nf = 0; nf < 4; ++nf)
        #pragma unroll
        for (int r = 0; r < 4; ++r) {
            int row = bm + wm + mf * 16 + l4 * 4 + r;
            int col = bn + wn + nf * 16 + l15;
            float v = acc[mf][nf][r] + bias[col];
            if constexpr (EPI == 0) {
                int bw_ = row >> 6, n_ = row & 63;
                if (col < 256) {
                    float q = v * 0.17677669529663687f;   // * hd^-0.5 (after bias, matching ref)
                    int h = col >> 5, d = col & 31;
                    qb[(((size_t)bw_ * 8 + h) * 64 + n_) * 32 + d] = (bf16)q;
                } else if (col < 512) {
                    int c2 = col - 256; int h = c2 >> 5, d = c2 & 31;
                    kb[(((size_t)bw_ * 8 + h) * 64 + n_) * 32 + d] = (bf16)v;
                } else {
                    int c2 = col - 512; int h = c2 >> 5, d = c2 & 31;
                    vtb[(((size_t)bw_ * 8 + h) * 32 + d) * 64 + n_] = (bf16)v;  // V transposed [hd][n]
                }
            } else if constexpr (EPI == 1) {
                int bw_ = row >> 6, n_ = row & 63;
                int b = bw_ >> 8, w = bw_ & 255;
                int wh = w >> 4, ww = w & 15;
                int ii = n_ >> 3, jj = n_ & 7;
                int ph = (wh * 8 + ii + 4) & 127, pw = (ww * 8 + jj + 4) & 127;
                size_t gidx = ((size_t)(b * LTOK + ph * 128 + pw)) * CDIM + col;
                outf[gidx] = add_f32[gidx] + v;
            } else if constexpr (EPI == 2) {
                outb[(size_t)row * N + col] = (bf16)gelu_exact(v);
            } else {
                size_t gidx = (size_t)(row0 + row) * N + col;
                outf[gidx] = v + add_f32[gidx];     // in-place residual add (same thread)
            }
        }
}

// ---------------- attention: one wave per (window, head) ----------------
__global__ __launch_bounds__(256) void attn_kernel(
    const bf16* __restrict__ qb, const bf16* __restrict__ kb, const bf16* __restrict__ vtb,
    const float* __restrict__ btab, bf16* __restrict__ ao)
{
    __shared__ bf16 P[4][64][72];
    int wid = threadIdx.x >> 6, lane = threadIdx.x & 63;
    int pair = blockIdx.x * 4 + wid;          // 8192 pairs
    int bw = pair >> 3, h = pair & 7;
    int l15 = lane & 15, l4 = lane >> 4;
    const bf16* Q  = qb  + ((size_t)bw * 8 + h) * 64 * 32;
    const bf16* Kp = kb  + ((size_t)bw * 8 + h) * 64 * 32;
    const bf16* Vt = vtb + ((size_t)bw * 8 + h) * 32 * 64;

    bf16x8 aq[4], bk[4];
    #pragma unroll
    for (int mf = 0; mf < 4; ++mf) aq[mf] = *(const bf16x8*)(Q  + (mf * 16 + l15) * 32 + 8 * l4);
    #pragma unroll
    for (int nf = 0; nf < 4; ++nf) bk[nf] = *(const bf16x8*)(Kp + (nf * 16 + l15) * 32 + 8 * l4);
    f32x4 s[4][4] = {};
    #pragma unroll
    for (int mf = 0; mf < 4; ++mf)
        #pragma unroll
        for (int nf = 0; nf < 4; ++nf)
            s[mf][nf] = __builtin_amdgcn_mfma_f32_16x16x32_bf16(aq[mf], bk[nf], s[mf][nf], 0, 0, 0);

    int w = bw & 255, wh = w >> 4, ww = w & 15;
    int ccode[4];
    #pragma unroll
    for (int nf = 0; nf < 4; ++nf) {
        int m_ = nf * 16 + l15;
        int hc = (wh == 15) ? (((m_ >> 3) < 4) ? 1 : 2) : 0;
        int wc = (ww == 15) ? (((m_ & 7) < 4) ? 1 : 2) : 0;
        ccode[nf] = hc * 3 + wc;
    }
    float rs[4][4];
    #pragma unroll
    for (int mf = 0; mf < 4; ++mf) {
        #pragma unroll
        for (int r = 0; r < 4; ++r) {
            int n_ = mf * 16 + l4 * 4 + r;
            int hc = (wh == 15) ? (((n_ >> 3) < 4) ? 1 : 2) : 0;
            int wc = (ww == 15) ? (((n_ & 7) < 4) ? 1 : 2) : 0;
            int rcode = hc * 3 + wc;
            float sv[4];
            float mx = -1e30f;
            #pragma unroll
            for (int nf = 0; nf < 4; ++nf) {
                int m_ = nf * 16 + l15;
                float t = s[mf][nf][r] + btab[(h * 64 + n_) * 64 + m_];
                if (ccode[nf] != rcode) t -= 100.0f;
                sv[nf] = t;
                mx = fmaxf(mx, t);
            }
            #pragma unroll
            for (int msk = 1; msk < 16; msk <<= 1) mx = fmaxf(mx, __shfl_xor(mx, msk));
            float sum = 0.0f;
            #pragma unroll
            for (int nf = 0; nf < 4; ++nf) { sv[nf] = __expf(sv[nf] - mx); sum += sv[nf]; }
            #pragma unroll
            for (int msk = 1; msk < 16; msk <<= 1) sum += __shfl_xor(sum, msk);
            rs[mf][r] = sum;
            #pragma unroll
            for (int nf = 0; nf < 4; ++nf) P[wid][n_][nf * 16 + l15] = (bf16)sv[nf];
        }
    }
    __syncthreads();

    f32x4 o[4][2] = {};
    #pragma unroll
    for (int kf = 0; kf < 2; ++kf) {
        bf16x8 bv[2];
        #pragma unroll
        for (int nf = 0; nf < 2; ++nf) bv[nf] = *(const bf16x8*)(Vt + (nf * 16 + l15) * 64 + kf * 32 + 8 * l4);
        #pragma unroll
        for (int mf = 0; mf < 4; ++mf) {
            bf16x8 pa = *(const bf16x8*)(&P[wid][mf * 16 + l15][kf * 32 + 8 * l4]);
            #pragma unroll
            for (int nf = 0; nf < 2; ++nf)
                o[mf][nf] = __builtin_amdgcn_mfma_f32_16x16x32_bf16(pa, bv[nf], o[mf][nf], 0, 0, 0);
        }
    }
    #pragma unroll
    for (int mf = 0; mf < 4; ++mf)
      #pragma unroll
      for (int nf = 0; nf < 2; ++nf)
        #pragma unroll
        for (int r = 0; r < 4; ++r) {
            int n_ = mf * 16 + l4 * 4 + r;
            int d = nf * 16 + l15;
            float val = o[mf][nf][r] / rs[mf][r];
            ao[((size_t)bw * 64 + n_) * CDIM + h * 32 + d] = (bf16)val;
        }
}

// ---------------- depthwise 3x3 conv + gelu (chunk-local h1/h2, global coords from pix0) ----------------
__global__ void dwconv_kernel(const bf16* __restrict__ h1, const float* __restrict__ dww,
                              const float* __restrict__ dwb, bf16* __restrict__ h2, int pix0) {
    int gid = blockIdx.x * 256 + threadIdx.x;   // npix*128
    int c8 = (gid & 127) * 8;
    int lpix = gid >> 7;
    int pix = pix0 + lpix;
    int b = pix >> 14, p = pix & 16383;
    int ph = p >> 7, pw = p & 127;
    float acc[8];
    #pragma unroll
    for (int j = 0; j < 8; ++j) acc[j] = dwb[c8 + j];
    #pragma unroll
    for (int dy = -1; dy <= 1; ++dy) {
        int y = ph + dy;
        if ((unsigned)y >= 128u) continue;
        #pragma unroll
        for (int dx = -1; dx <= 1; ++dx) {
            int x = pw + dx;
            if ((unsigned)x >= 128u) continue;
            int ln_ = b * LTOK + y * 128 + x - pix0;    // chunk-local neighbor pixel
            bf16x8 v = *(const bf16x8*)(h1 + (size_t)ln_ * HIDDEN + c8);
            const float* wp = dww + ((dy + 1) * 3 + (dx + 1)) * HIDDEN + c8;
            #pragma unroll
            for (int j = 0; j < 8; ++j) acc[j] += (float)v[j] * wp[j];
        }
    }
    bf16x8 o;
    #pragma unroll
    for (int j = 0; j < 8; ++j) o[j] = (bf16)gelu_exact(acc[j]);
    *(bf16x8*)(h2 + (size_t)lpix * HIDDEN + c8) = o;
}

// ---------------- launch ----------------
extern "C" void kernel_launch(void* const* d_in, const int* in_sizes, int n_in,
                              void* d_out, int out_size, void* d_ws, size_t ws_size,
                              hipStream_t stream) {
    const float* x    = (const float*)d_in[0];
    const float* g1   = (const float*)d_in[1];
    const float* be1  = (const float*)d_in[2];
    const float* wq   = (const float*)d_in[3];
    const float* bq   = (const float*)d_in[4];
    const float* wkv  = (const float*)d_in[5];
    const float* bkv  = (const float*)d_in[6];
    const float* rpb  = (const float*)d_in[7];
    const float* wo   = (const float*)d_in[8];
    const float* bo   = (const float*)d_in[9];
    const float* g2   = (const float*)d_in[10];
    const float* be2  = (const float*)d_in[11];
    const float* w1   = (const float*)d_in[12];
    const float* bl1  = (const float*)d_in[13];
    const float* dww  = (const float*)d_in[14];
    const float* dwb  = (const float*)d_in[15];
    const float* w2   = (const float*)d_in[16];
    const float* bl2  = (const float*)d_in[17];
    float* out = (float*)d_out;

    // ---- workspace layout (total ~162 MiB) ----
    char* ws = (char*)d_ws;
    bf16*  wqkvt  = (bf16*)(ws + 0);                      // 768*256*2      = 393216
    float* biasq  = (float*)(ws + 393216);                // 768*4          = 3072
    bf16*  wot    = (bf16*)(ws + 396288);                 // 256*256*2      = 131072
    bf16*  w1t    = (bf16*)(ws + 527360);                 // 1024*256*2     = 524288
    bf16*  w2t    = (bf16*)(ws + 1051648);                // 256*1024*2     = 524288
    float* btab   = (float*)(ws + 1575936);               // 8*64*64*4      = 131072
    char*  R1     = ws + 1707008;                         // 96 MiB region
    char*  R2     = ws + 1707008 + 100663296;             // 64 MiB region   (end ~162 MiB)

    bf16*  qb   = (bf16*)(R1 + 0);                        // 32 MiB
    bf16*  kb   = (bf16*)(R1 + 33554432);                 // 32 MiB
    bf16*  vtb  = (bf16*)(R1 + 67108864);                 // 32 MiB
    bf16*  yln  = (bf16*)(R1 + 0);                        // over qb (dead after attn)
    bf16*  h2c  = (bf16*)(R1 + 33554432);                 // 64 MiB chunk, over kb+vtb (dead)

    bf16*  ao   = (bf16*)(R2 + 0);                        // 32 MiB
    bf16*  h1c  = (bf16*)(R2 + 0);                        // 64 MiB chunk, over ao (dead after proj)

    bf16*  xw   = (bf16*)d_out;                           // 32 MiB inside d_out (dead before proj)
    float* x2   = (float*)d_out;                          // f32 residual stream lives in d_out

    // prep
    prep_qkvw<<<768, 256, 0, stream>>>(wq, bq, wkv, bkv, wqkvt, biasq);
    prep_wt<<<256, 256, 0, stream>>>(wo, wot, 256, 256);
    prep_wt<<<1024, 256, 0, stream>>>(w1, w1t, 256, 1024);
    prep_wt<<<1024, 256, 0, stream>>>(w2, w2t, 1024, 256);
    prep_btab<<<128, 256, 0, stream>>>(rpb, btab);

    // LN1 + shift + window partition -> xw (in d_out)
    ln1_winpart<<<16384, 256, 0, stream>>>(x, g1, be1, xw);

    // QKV
    gemm_bt<0><<<dim3(512, 6), 256, 0, stream>>>(xw, wqkvt, biasq, TOK_TOTAL, 768, 256, 0,
                                                 nullptr, nullptr, nullptr, qb, kb, vtb);
    // attention
    attn_kernel<<<2048, 256, 0, stream>>>(qb, kb, vtb, btab, ao);

    // proj + win_rev + roll + residual -> x2 (f32, in d_out; xw dead)
    gemm_bt<1><<<dim3(512, 2), 256, 0, stream>>>(ao, wot, bo, TOK_TOTAL, 256, 256, 0,
                                                 nullptr, x2, x, nullptr, nullptr, nullptr);
    // LN2 (reads d_out) -> yln
    ln2_kernel<<<16384, 256, 0, stream>>>(x2, g2, be2, yln);

    // MLP1+gelu -> conv+gelu -> MLP2+residual, chunked by 2 batches (exact: no cross-batch halo)
    for (int c = 0; c < 2; ++c) {
        int pix0 = c * 32768;
        gemm_bt<2><<<dim3(256, 8), 256, 0, stream>>>(yln + (size_t)pix0 * CDIM, w1t, bl1,
                                                     32768, HIDDEN, 256, 0,
                                                     h1c, nullptr, nullptr, nullptr, nullptr, nullptr);
        dwconv_kernel<<<16384, 256, 0, stream>>>(h1c, dww, dwb, h2c, pix0);
        gemm_bt<3><<<dim3(256, 2), 256, 0, stream>>>(h2c, w2t, bl2, 32768, 256, HIDDEN, pix0,
                                                     nullptr, x2, x2, nullptr, nullptr, nullptr);
    }
}

// Round 8
// 646.731 us; speedup vs baseline: 1.0416x; 1.0416x over previous
//
#include <hip/hip_runtime.h>
#include <hip/hip_bf16.h>
#include <math.h>

typedef __bf16 bf16;
typedef __bf16 bf16x8 __attribute__((ext_vector_type(8)));
typedef __bf16 bf16x4 __attribute__((ext_vector_type(4)));
typedef float  f32x4  __attribute__((ext_vector_type(4)));

#define HRES 128
#define WRES 128
#define CDIM 256
#define NHEADS 8
#define HD 32
#define NWIN 64      // tokens per window
#define LTOK 16384   // tokens per image
#define BATCH 4
#define TOK_TOTAL 65536
#define HIDDEN 1024

__device__ __forceinline__ float gelu_exact(float v) {
    return 0.5f * v * (1.0f + erff(v * 0.70710678118654752f));
}

// async global->LDS, 16 bytes per lane (dest must be wave-uniform base + lane*16)
__device__ __forceinline__ void gld16(const bf16* g, bf16* l) {
    __builtin_amdgcn_global_load_lds(
        (const __attribute__((address_space(1))) unsigned int*)g,
        (__attribute__((address_space(3))) unsigned int*)l, 16, 0, 0);
}

// ---------------- prep kernels ----------------

// Combined QKV weight transpose -> Bt [768][256] bf16, bias_qkv [768] f32
__global__ void prep_qkvw(const float* __restrict__ wq, const float* __restrict__ bq,
                          const float* __restrict__ wkv, const float* __restrict__ bkv,
                          bf16* __restrict__ bt, float* __restrict__ bias) {
    int idx = blockIdx.x * 256 + threadIdx.x;   // 768*256
    int c = idx >> 8, k = idx & 255;
    float v = (c < 256) ? wq[k * 256 + c] : wkv[k * 512 + (c - 256)];
    bt[idx] = (bf16)v;
    if (k == 0) bias[c] = (c < 256) ? bq[c] : bkv[c - 256];
}

// generic transpose to bf16: wt[n*K+k] = w[k*N+n]
__global__ void prep_wt(const float* __restrict__ w, bf16* __restrict__ wt, int K, int N) {
    int idx = blockIdx.x * 256 + threadIdx.x;
    if (idx >= K * N) return;
    int n = idx / K, k = idx - n * K;
    wt[idx] = (bf16)w[(size_t)k * N + n];
}

// rel-pos bias table: btab[h][n][m]
__global__ void prep_btab(const float* __restrict__ rpb, float* __restrict__ btab) {
    int idx = blockIdx.x * 256 + threadIdx.x;   // 8*64*64 = 32768
    int h = idx >> 12;
    int n = (idx >> 6) & 63;
    int m = idx & 63;
    int i1 = n >> 3, j1 = n & 7, i2 = m >> 3, j2 = m & 7;
    int rel = (i1 - i2 + 7) * 15 + (j1 - j2 + 7);
    btab[idx] = rpb[rel * NHEADS + h];
}

// ---------------- LN kernels ----------------

// LN1 + cyclic shift(-4,-4) + window partition; out xw bf16 [65536][256] in window-token order
__global__ void ln1_winpart(const float* __restrict__ x, const float* __restrict__ g,
                            const float* __restrict__ be, bf16* __restrict__ xw) {
    int wv = (blockIdx.x * blockDim.x + threadIdx.x) >> 6;   // token in window order
    int lane = threadIdx.x & 63;
    int bw = wv >> 6, n = wv & 63;
    int b = bw >> 8, w = bw & 255;
    int wh = w >> 4, ww = w & 15;
    int i = n >> 3, j = n & 7;
    int ph = (wh * 8 + i + 4) & 127, pw = (ww * 8 + j + 4) & 127;
    const float* row = x + ((size_t)(b * LTOK + ph * 128 + pw)) * CDIM;
    float4 v = *(const float4*)(row + lane * 4);
    float s = v.x + v.y + v.z + v.w;
    float ss = v.x * v.x + v.y * v.y + v.z * v.z + v.w * v.w;
    #pragma unroll
    for (int m = 1; m < 64; m <<= 1) { s += __shfl_xor(s, m); ss += __shfl_xor(ss, m); }
    float mu = s * (1.0f / 256.0f);
    float var = ss * (1.0f / 256.0f) - mu * mu;
    float inv = rsqrtf(var + 1e-5f);
    int c0 = lane * 4;
    bf16x4 o;
    o[0] = (bf16)((v.x - mu) * inv * g[c0 + 0] + be[c0 + 0]);
    o[1] = (bf16)((v.y - mu) * inv * g[c0 + 1] + be[c0 + 1]);
    o[2] = (bf16)((v.z - mu) * inv * g[c0 + 2] + be[c0 + 2]);
    o[3] = (bf16)((v.w - mu) * inv * g[c0 + 3] + be[c0 + 3]);
    *(bf16x4*)(xw + (size_t)wv * CDIM + c0) = o;
}

// LN2 (identity token order): x2 f32 -> yln bf16
__global__ void ln2_kernel(const float* __restrict__ x2, const float* __restrict__ g,
                           const float* __restrict__ be, bf16* __restrict__ y) {
    int t = (blockIdx.x * blockDim.x + threadIdx.x) >> 6;
    int lane = threadIdx.x & 63;
    const float* row = x2 + (size_t)t * CDIM;
    float4 v = *(const float4*)(row + lane * 4);
    float s = v.x + v.y + v.z + v.w;
    float ss = v.x * v.x + v.y * v.y + v.z * v.z + v.w * v.w;
    #pragma unroll
    for (int m = 1; m < 64; m <<= 1) { s += __shfl_xor(s, m); ss += __shfl_xor(ss, m); }
    float mu = s * (1.0f / 256.0f);
    float var = ss * (1.0f / 256.0f) - mu * mu;
    float inv = rsqrtf(var + 1e-5f);
    int c0 = lane * 4;
    bf16x4 o;
    o[0] = (bf16)((v.x - mu) * inv * g[c0 + 0] + be[c0 + 0]);
    o[1] = (bf16)((v.y - mu) * inv * g[c0 + 1] + be[c0 + 1]);
    o[2] = (bf16)((v.z - mu) * inv * g[c0 + 2] + be[c0 + 2]);
    o[3] = (bf16)((v.w - mu) * inv * g[c0 + 3] + be[c0 + 3]);
    *(bf16x4*)(y + (size_t)t * CDIM + c0) = o;
}

// ---------------- generic MFMA GEMM (A[M,K] bf16 row-major, Bt[N,K] bf16 row-major) ----------------
// Double-buffered LDS + counted vmcnt(8) pipeline + XOR-swizzled LDS (both-sides: pre-swizzled
// global source column, swizzled ds_read address; linear global_load_lds dest).
// EPI: 0=QKV scatter, 1=proj(win_rev+roll+residual->f32), 2=MLP1(gelu->bf16), 3=MLP2(+res in-place f32)
template <int EPI>
__global__ __launch_bounds__(256) void gemm_bt(
    const bf16* __restrict__ A, const bf16* __restrict__ Bt,
    const float* __restrict__ bias, int M, int N, int K, int row0,
    bf16* __restrict__ outb, float* __restrict__ outf, const float* __restrict__ add_f32,
    bf16* __restrict__ qb, bf16* __restrict__ kb, bf16* __restrict__ vtb)
{
    __shared__ bf16 As[2][128][64];
    __shared__ bf16 Bs[2][128][64];
    int tid = threadIdx.x;
    int lane = tid & 63;
    int wid = tid >> 6;
    int bm = blockIdx.x * 128, bn = blockIdx.y * 128;
    int wm = (wid >> 1) * 64, wn = (wid & 1) * 64;
    int l15 = lane & 15, l4 = lane >> 4;
    f32x4 acc[4][4] = {};

    const bf16* Abase = A + (size_t)bm * K;
    const bf16* Bbase = Bt + (size_t)bn * K;

    // stage tile k0 into buffer b: linear LDS dest (wave-uniform base + lane*16),
    // source column pre-swizzled so that a swizzled READ returns the right data.
    auto stage = [&](int b, int k0) {
        #pragma unroll
        for (int it = 0; it < 4; ++it) {
            int e = (it * 256 + tid) * 8;          // linear element slot in 128x64 tile
            int r = e >> 6, kks = e & 63;
            int kk = kks ^ ((r & 7) << 3);         // involution: source col for this slot
            gld16(Abase + (size_t)r * K + k0 + kk, &As[b][0][0] + e);
            gld16(Bbase + (size_t)r * K + k0 + kk, &Bs[b][0][0] + e);
        }
    };

    int nt = K >> 6;
    stage(0, 0);
    int cur = 0;
    for (int t = 0; t < nt; ++t) {
        if (t + 1 < nt) {
            stage(cur ^ 1, (t + 1) << 6);
            asm volatile("s_waitcnt vmcnt(8)" ::: "memory");   // own loads for tile t done; t+1 stays in flight
        } else {
            asm volatile("s_waitcnt vmcnt(0)" ::: "memory");
        }
        __builtin_amdgcn_s_barrier();                          // all waves' tile-t writes visible
        __builtin_amdgcn_sched_barrier(0);
        #pragma unroll
        for (int kh = 0; kh < 2; ++kh) {
            bf16x8 af[4], bfr[4];
            int col = kh * 32 + 8 * l4;
            #pragma unroll
            for (int mf = 0; mf < 4; ++mf) {
                int row = wm + mf * 16 + l15;
                af[mf] = *(const bf16x8*)(&As[cur][0][0] + row * 64 + (col ^ ((row & 7) << 3)));
            }
            #pragma unroll
            for (int nf = 0; nf < 4; ++nf) {
                int row = wn + nf * 16 + l15;
                bfr[nf] = *(const bf16x8*)(&Bs[cur][0][0] + row * 64 + (col ^ ((row & 7) << 3)));
            }
            #pragma unroll
            for (int mf = 0; mf < 4; ++mf)
                #pragma unroll
                for (int nf = 0; nf < 4; ++nf)
                    acc[mf][nf] = __builtin_amdgcn_mfma_f32_16x16x32_bf16(af[mf], bfr[nf], acc[mf][nf], 0, 0, 0);
        }
        __builtin_amdgcn_s_barrier();                          // reads of buf[cur] done before next overwrite
        cur ^= 1;
    }

    #pragma unroll
    for (int mf = 0; mf < 4; ++mf)
      #pragma unroll
      for (int nf = 0; nf < 4; ++nf)
        #pragma unroll
        for (int r = 0; r < 4; ++r) {
            int row = bm + wm + mf * 16 + l4 * 4 + r;
            int col = bn + wn + nf * 16 + l15;
            float v = acc[mf][nf][r] + bias[col];
            if constexpr (EPI == 0) {
                int bw_ = row >> 6, n_ = row & 63;
                if (col < 256) {
                    float q = v * 0.17677669529663687f;   // * hd^-0.5 (after bias, matching ref)
                    int h = col >> 5, d = col & 31;
                    qb[(((size_t)bw_ * 8 + h) * 64 + n_) * 32 + d] = (bf16)q;
                } else if (col < 512) {
                    int c2 = col - 256; int h = c2 >> 5, d = c2 & 31;
                    kb[(((size_t)bw_ * 8 + h) * 64 + n_) * 32 + d] = (bf16)v;
                } else {
                    int c2 = col - 512; int h = c2 >> 5, d = c2 & 31;
                    vtb[(((size_t)bw_ * 8 + h) * 32 + d) * 64 + n_] = (bf16)v;  // V transposed [hd][n]
                }
            } else if constexpr (EPI == 1) {
                int bw_ = row >> 6, n_ = row & 63;
                int b = bw_ >> 8, w = bw_ & 255;
                int wh = w >> 4, ww = w & 15;
                int ii = n_ >> 3, jj = n_ & 7;
                int ph = (wh * 8 + ii + 4) & 127, pw = (ww * 8 + jj + 4) & 127;
                size_t gidx = ((size_t)(b * LTOK + ph * 128 + pw)) * CDIM + col;
                outf[gidx] = add_f32[gidx] + v;
            } else if constexpr (EPI == 2) {
                outb[(size_t)row * N + col] = (bf16)gelu_exact(v);
            } else {
                size_t gidx = (size_t)(row0 + row) * N + col;
                outf[gidx] = v + add_f32[gidx];     // in-place residual add (same thread)
            }
        }
}

// ---------------- attention: one wave per (window, head) ----------------
__global__ __launch_bounds__(256) void attn_kernel(
    const bf16* __restrict__ qb, const bf16* __restrict__ kb, const bf16* __restrict__ vtb,
    const float* __restrict__ btab, bf16* __restrict__ ao)
{
    __shared__ bf16 P[4][64][72];
    int wid = threadIdx.x >> 6, lane = threadIdx.x & 63;
    int pair = blockIdx.x * 4 + wid;          // 8192 pairs
    int bw = pair >> 3, h = pair & 7;
    int l15 = lane & 15, l4 = lane >> 4;
    const bf16* Q  = qb  + ((size_t)bw * 8 + h) * 64 * 32;
    const bf16* Kp = kb  + ((size_t)bw * 8 + h) * 64 * 32;
    const bf16* Vt = vtb + ((size_t)bw * 8 + h) * 32 * 64;

    bf16x8 aq[4], bk[4];
    #pragma unroll
    for (int mf = 0; mf < 4; ++mf) aq[mf] = *(const bf16x8*)(Q  + (mf * 16 + l15) * 32 + 8 * l4);
    #pragma unroll
    for (int nf = 0; nf < 4; ++nf) bk[nf] = *(const bf16x8*)(Kp + (nf * 16 + l15) * 32 + 8 * l4);
    f32x4 s[4][4] = {};
    #pragma unroll
    for (int mf = 0; mf < 4; ++mf)
        #pragma unroll
        for (int nf = 0; nf < 4; ++nf)
            s[mf][nf] = __builtin_amdgcn_mfma_f32_16x16x32_bf16(aq[mf], bk[nf], s[mf][nf], 0, 0, 0);

    int w = bw & 255, wh = w >> 4, ww = w & 15;
    int ccode[4];
    #pragma unroll
    for (int nf = 0; nf < 4; ++nf) {
        int m_ = nf * 16 + l15;
        int hc = (wh == 15) ? (((m_ >> 3) < 4) ? 1 : 2) : 0;
        int wc = (ww == 15) ? (((m_ & 7) < 4) ? 1 : 2) : 0;
        ccode[nf] = hc * 3 + wc;
    }
    float rs[4][4];
    #pragma unroll
    for (int mf = 0; mf < 4; ++mf) {
        #pragma unroll
        for (int r = 0; r < 4; ++r) {
            int n_ = mf * 16 + l4 * 4 + r;
            int hc = (wh == 15) ? (((n_ >> 3) < 4) ? 1 : 2) : 0;
            int wc = (ww == 15) ? (((n_ & 7) < 4) ? 1 : 2) : 0;
            int rcode = hc * 3 + wc;
            float sv[4];
            float mx = -1e30f;
            #pragma unroll
            for (int nf = 0; nf < 4; ++nf) {
                int m_ = nf * 16 + l15;
                float t = s[mf][nf][r] + btab[(h * 64 + n_) * 64 + m_];
                if (ccode[nf] != rcode) t -= 100.0f;
                sv[nf] = t;
                mx = fmaxf(mx, t);
            }
            #pragma unroll
            for (int msk = 1; msk < 16; msk <<= 1) mx = fmaxf(mx, __shfl_xor(mx, msk));
            float sum = 0.0f;
            #pragma unroll
            for (int nf = 0; nf < 4; ++nf) { sv[nf] = __expf(sv[nf] - mx); sum += sv[nf]; }
            #pragma unroll
            for (int msk = 1; msk < 16; msk <<= 1) sum += __shfl_xor(sum, msk);
            rs[mf][r] = sum;
            #pragma unroll
            for (int nf = 0; nf < 4; ++nf) P[wid][n_][nf * 16 + l15] = (bf16)sv[nf];
        }
    }
    __syncthreads();

    f32x4 o[4][2] = {};
    #pragma unroll
    for (int kf = 0; kf < 2; ++kf) {
        bf16x8 bv[2];
        #pragma unroll
        for (int nf = 0; nf < 2; ++nf) bv[nf] = *(const bf16x8*)(Vt + (nf * 16 + l15) * 64 + kf * 32 + 8 * l4);
        #pragma unroll
        for (int mf = 0; mf < 4; ++mf) {
            bf16x8 pa = *(const bf16x8*)(&P[wid][mf * 16 + l15][kf * 32 + 8 * l4]);
            #pragma unroll
            for (int nf = 0; nf < 2; ++nf)
                o[mf][nf] = __builtin_amdgcn_mfma_f32_16x16x32_bf16(pa, bv[nf], o[mf][nf], 0, 0, 0);
        }
    }
    #pragma unroll
    for (int mf = 0; mf < 4; ++mf)
      #pragma unroll
      for (int nf = 0; nf < 2; ++nf)
        #pragma unroll
        for (int r = 0; r < 4; ++r) {
            int n_ = mf * 16 + l4 * 4 + r;
            int d = nf * 16 + l15;
            float val = o[mf][nf][r] / rs[mf][r];
            ao[((size_t)bw * 64 + n_) * CDIM + h * 32 + d] = (bf16)val;
        }
}

// ---------------- depthwise 3x3 conv + gelu (chunk-local h1/h2, global coords from pix0) ----------------
__global__ void dwconv_kernel(const bf16* __restrict__ h1, const float* __restrict__ dww,
                              const float* __restrict__ dwb, bf16* __restrict__ h2, int pix0) {
    int gid = blockIdx.x * 256 + threadIdx.x;   // npix*128
    int c8 = (gid & 127) * 8;
    int lpix = gid >> 7;
    int pix = pix0 + lpix;
    int b = pix >> 14, p = pix & 16383;
    int ph = p >> 7, pw = p & 127;
    float acc[8];
    #pragma unroll
    for (int j = 0; j < 8; ++j) acc[j] = dwb[c8 + j];
    #pragma unroll
    for (int dy = -1; dy <= 1; ++dy) {
        int y = ph + dy;
        if ((unsigned)y >= 128u) continue;
        #pragma unroll
        for (int dx = -1; dx <= 1; ++dx) {
            int x = pw + dx;
            if ((unsigned)x >= 128u) continue;
            int ln_ = b * LTOK + y * 128 + x - pix0;    // chunk-local neighbor pixel
            bf16x8 v = *(const bf16x8*)(h1 + (size_t)ln_ * HIDDEN + c8);
            const float* wp = dww + ((dy + 1) * 3 + (dx + 1)) * HIDDEN + c8;
            #pragma unroll
            for (int j = 0; j < 8; ++j) acc[j] += (float)v[j] * wp[j];
        }
    }
    bf16x8 o;
    #pragma unroll
    for (int j = 0; j < 8; ++j) o[j] = (bf16)gelu_exact(acc[j]);
    *(bf16x8*)(h2 + (size_t)lpix * HIDDEN + c8) = o;
}

// ---------------- launch ----------------
extern "C" void kernel_launch(void* const* d_in, const int* in_sizes, int n_in,
                              void* d_out, int out_size, void* d_ws, size_t ws_size,
                              hipStream_t stream) {
    const float* x    = (const float*)d_in[0];
    const float* g1   = (const float*)d_in[1];
    const float* be1  = (const float*)d_in[2];
    const float* wq   = (const float*)d_in[3];
    const float* bq   = (const float*)d_in[4];
    const float* wkv  = (const float*)d_in[5];
    const float* bkv  = (const float*)d_in[6];
    const float* rpb  = (const float*)d_in[7];
    const float* wo   = (const float*)d_in[8];
    const float* bo   = (const float*)d_in[9];
    const float* g2   = (const float*)d_in[10];
    const float* be2  = (const float*)d_in[11];
    const float* w1   = (const float*)d_in[12];
    const float* bl1  = (const float*)d_in[13];
    const float* dww  = (const float*)d_in[14];
    const float* dwb  = (const float*)d_in[15];
    const float* w2   = (const float*)d_in[16];
    const float* bl2  = (const float*)d_in[17];
    float* out = (float*)d_out;

    // ---- workspace layout (total ~162 MiB) ----
    char* ws = (char*)d_ws;
    bf16*  wqkvt  = (bf16*)(ws + 0);                      // 768*256*2      = 393216
    float* biasq  = (float*)(ws + 393216);                // 768*4          = 3072
    bf16*  wot    = (bf16*)(ws + 396288);                 // 256*256*2      = 131072
    bf16*  w1t    = (bf16*)(ws + 527360);                 // 1024*256*2     = 524288
    bf16*  w2t    = (bf16*)(ws + 1051648);                // 256*1024*2     = 524288
    float* btab   = (float*)(ws + 1575936);               // 8*64*64*4      = 131072
    char*  R1     = ws + 1707008;                         // 96 MiB region
    char*  R2     = ws + 1707008 + 100663296;             // 64 MiB region   (end ~162 MiB)

    bf16*  qb   = (bf16*)(R1 + 0);                        // 32 MiB
    bf16*  kb   = (bf16*)(R1 + 33554432);                 // 32 MiB
    bf16*  vtb  = (bf16*)(R1 + 67108864);                 // 32 MiB
    bf16*  yln  = (bf16*)(R1 + 0);                        // over qb (dead after attn)
    bf16*  h2c  = (bf16*)(R1 + 33554432);                 // 64 MiB chunk, over kb+vtb (dead)

    bf16*  ao   = (bf16*)(R2 + 0);                        // 32 MiB
    bf16*  h1c  = (bf16*)(R2 + 0);                        // 64 MiB chunk, over ao (dead after proj)

    bf16*  xw   = (bf16*)d_out;                           // 32 MiB inside d_out (dead before proj)
    float* x2   = (float*)d_out;                          // f32 residual stream lives in d_out

    // prep
    prep_qkvw<<<768, 256, 0, stream>>>(wq, bq, wkv, bkv, wqkvt, biasq);
    prep_wt<<<256, 256, 0, stream>>>(wo, wot, 256, 256);
    prep_wt<<<1024, 256, 0, stream>>>(w1, w1t, 256, 1024);
    prep_wt<<<1024, 256, 0, stream>>>(w2, w2t, 1024, 256);
    prep_btab<<<128, 256, 0, stream>>>(rpb, btab);

    // LN1 + shift + window partition -> xw (in d_out)
    ln1_winpart<<<16384, 256, 0, stream>>>(x, g1, be1, xw);

    // QKV
    gemm_bt<0><<<dim3(512, 6), 256, 0, stream>>>(xw, wqkvt, biasq, TOK_TOTAL, 768, 256, 0,
                                                 nullptr, nullptr, nullptr, qb, kb, vtb);
    // attention
    attn_kernel<<<2048, 256, 0, stream>>>(qb, kb, vtb, btab, ao);

    // proj + win_rev + roll + residual -> x2 (f32, in d_out; xw dead)
    gemm_bt<1><<<dim3(512, 2), 256, 0, stream>>>(ao, wot, bo, TOK_TOTAL, 256, 256, 0,
                                                 nullptr, x2, x, nullptr, nullptr, nullptr);
    // LN2 (reads d_out) -> yln
    ln2_kernel<<<16384, 256, 0, stream>>>(x2, g2, be2, yln);

    // MLP1+gelu -> conv+gelu -> MLP2+residual, chunked by 2 batches (exact: no cross-batch halo)
    for (int c = 0; c < 2; ++c) {
        int pix0 = c * 32768;
        gemm_bt<2><<<dim3(256, 8), 256, 0, stream>>>(yln + (size_t)pix0 * CDIM, w1t, bl1,
                                                     32768, HIDDEN, 256, 0,
                                                     h1c, nullptr, nullptr, nullptr, nullptr, nullptr);
        dwconv_kernel<<<16384, 256, 0, stream>>>(h1c, dww, dwb, h2c, pix0);
        gemm_bt<3><<<dim3(256, 2), 256, 0, stream>>>(h2c, w2t, bl2, 32768, 256, HIDDEN, pix0,
                                                     nullptr, x2, x2, nullptr, nullptr, nullptr);
    }
}

// Round 9
// 643.165 us; speedup vs baseline: 1.0474x; 1.0055x over previous
//
#include <hip/hip_runtime.h>
#include <hip/hip_bf16.h>
#include <math.h>

typedef __bf16 bf16;
typedef __bf16 bf16x8 __attribute__((ext_vector_type(8)));
typedef __bf16 bf16x4 __attribute__((ext_vector_type(4)));
typedef float  f32x4  __attribute__((ext_vector_type(4)));

#define HRES 128
#define WRES 128
#define CDIM 256
#define NHEADS 8
#define HD 32
#define NWIN 64      // tokens per window
#define LTOK 16384   // tokens per image
#define BATCH 4
#define TOK_TOTAL 65536
#define HIDDEN 1024

__device__ __forceinline__ float gelu_exact(float v) {
    return 0.5f * v * (1.0f + erff(v * 0.70710678118654752f));
}

// async global->LDS, 16 bytes per lane (dest must be wave-uniform base + lane*16)
__device__ __forceinline__ void gld16(const bf16* g, bf16* l) {
    __builtin_amdgcn_global_load_lds(
        (const __attribute__((address_space(1))) unsigned int*)g,
        (__attribute__((address_space(3))) unsigned int*)l, 16, 0, 0);
}

// ---------------- prep kernels ----------------

// Combined QKV weight transpose -> Bt [768][256] bf16, bias_qkv [768] f32
__global__ void prep_qkvw(const float* __restrict__ wq, const float* __restrict__ bq,
                          const float* __restrict__ wkv, const float* __restrict__ bkv,
                          bf16* __restrict__ bt, float* __restrict__ bias) {
    int idx = blockIdx.x * 256 + threadIdx.x;   // 768*256
    int c = idx >> 8, k = idx & 255;
    float v = (c < 256) ? wq[k * 256 + c] : wkv[k * 512 + (c - 256)];
    bt[idx] = (bf16)v;
    if (k == 0) bias[c] = (c < 256) ? bq[c] : bkv[c - 256];
}

// generic transpose to bf16: wt[n*K+k] = w[k*N+n]
__global__ void prep_wt(const float* __restrict__ w, bf16* __restrict__ wt, int K, int N) {
    int idx = blockIdx.x * 256 + threadIdx.x;
    if (idx >= K * N) return;
    int n = idx / K, k = idx - n * K;
    wt[idx] = (bf16)w[(size_t)k * N + n];
}

// rel-pos bias table: btab[h][n][m]
__global__ void prep_btab(const float* __restrict__ rpb, float* __restrict__ btab) {
    int idx = blockIdx.x * 256 + threadIdx.x;   // 8*64*64 = 32768
    int h = idx >> 12;
    int n = (idx >> 6) & 63;
    int m = idx & 63;
    int i1 = n >> 3, j1 = n & 7, i2 = m >> 3, j2 = m & 7;
    int rel = (i1 - i2 + 7) * 15 + (j1 - j2 + 7);
    btab[idx] = rpb[rel * NHEADS + h];
}

// ---------------- LN kernels ----------------

// LN1 + cyclic shift(-4,-4) + window partition; out xw bf16 [65536][256] in window-token order
__global__ void ln1_winpart(const float* __restrict__ x, const float* __restrict__ g,
                            const float* __restrict__ be, bf16* __restrict__ xw) {
    int wv = (blockIdx.x * blockDim.x + threadIdx.x) >> 6;   // token in window order
    int lane = threadIdx.x & 63;
    int bw = wv >> 6, n = wv & 63;
    int b = bw >> 8, w = bw & 255;
    int wh = w >> 4, ww = w & 15;
    int i = n >> 3, j = n & 7;
    int ph = (wh * 8 + i + 4) & 127, pw = (ww * 8 + j + 4) & 127;
    const float* row = x + ((size_t)(b * LTOK + ph * 128 + pw)) * CDIM;
    float4 v = *(const float4*)(row + lane * 4);
    float s = v.x + v.y + v.z + v.w;
    float ss = v.x * v.x + v.y * v.y + v.z * v.z + v.w * v.w;
    #pragma unroll
    for (int m = 1; m < 64; m <<= 1) { s += __shfl_xor(s, m); ss += __shfl_xor(ss, m); }
    float mu = s * (1.0f / 256.0f);
    float var = ss * (1.0f / 256.0f) - mu * mu;
    float inv = rsqrtf(var + 1e-5f);
    int c0 = lane * 4;
    bf16x4 o;
    o[0] = (bf16)((v.x - mu) * inv * g[c0 + 0] + be[c0 + 0]);
    o[1] = (bf16)((v.y - mu) * inv * g[c0 + 1] + be[c0 + 1]);
    o[2] = (bf16)((v.z - mu) * inv * g[c0 + 2] + be[c0 + 2]);
    o[3] = (bf16)((v.w - mu) * inv * g[c0 + 3] + be[c0 + 3]);
    *(bf16x4*)(xw + (size_t)wv * CDIM + c0) = o;
}

// LN2 (identity token order): x2 f32 -> yln bf16
__global__ void ln2_kernel(const float* __restrict__ x2, const float* __restrict__ g,
                           const float* __restrict__ be, bf16* __restrict__ y) {
    int t = (blockIdx.x * blockDim.x + threadIdx.x) >> 6;
    int lane = threadIdx.x & 63;
    const float* row = x2 + (size_t)t * CDIM;
    float4 v = *(const float4*)(row + lane * 4);
    float s = v.x + v.y + v.z + v.w;
    float ss = v.x * v.x + v.y * v.y + v.z * v.z + v.w * v.w;
    #pragma unroll
    for (int m = 1; m < 64; m <<= 1) { s += __shfl_xor(s, m); ss += __shfl_xor(ss, m); }
    float mu = s * (1.0f / 256.0f);
    float var = ss * (1.0f / 256.0f) - mu * mu;
    float inv = rsqrtf(var + 1e-5f);
    int c0 = lane * 4;
    bf16x4 o;
    o[0] = (bf16)((v.x - mu) * inv * g[c0 + 0] + be[c0 + 0]);
    o[1] = (bf16)((v.y - mu) * inv * g[c0 + 1] + be[c0 + 1]);
    o[2] = (bf16)((v.z - mu) * inv * g[c0 + 2] + be[c0 + 2]);
    o[3] = (bf16)((v.w - mu) * inv * g[c0 + 3] + be[c0 + 3]);
    *(bf16x4*)(y + (size_t)t * CDIM + c0) = o;
}

// ---------------- generic MFMA GEMM (A[M,K] bf16 row-major, Bt[N,K] bf16 row-major) ----------------
// BK=32 double-buffer + counted vmcnt(4) pipeline; 32 KB LDS -> 5 blocks/CU.
// XOR swizzle for 64B row stride: col ^= ((row>>1)&3)<<3 (2 lanes/bank-group = free).
// EPI: 0=QKV scatter, 1=proj(win_rev+roll+residual->f32), 2=MLP1(gelu->bf16), 3=MLP2(+res in-place f32)
template <int EPI>
__global__ __launch_bounds__(256) void gemm_bt(
    const bf16* __restrict__ A, const bf16* __restrict__ Bt,
    const float* __restrict__ bias, int M, int N, int K, int row0,
    bf16* __restrict__ outb, float* __restrict__ outf, const float* __restrict__ add_f32,
    bf16* __restrict__ qb, bf16* __restrict__ kb, bf16* __restrict__ vtb)
{
    constexpr int BK = 32;
    __shared__ bf16 As[2][128][BK];
    __shared__ bf16 Bs[2][128][BK];
    int tid = threadIdx.x;
    int lane = tid & 63;
    int wid = tid >> 6;
    int bm = blockIdx.x * 128, bn = blockIdx.y * 128;
    int wm = (wid >> 1) * 64, wn = (wid & 1) * 64;
    int l15 = lane & 15, l4 = lane >> 4;
    f32x4 acc[4][4] = {};

    const bf16* Abase = A + (size_t)bm * K;
    const bf16* Bbase = Bt + (size_t)bn * K;

    // stage tile k0 into buffer b: linear LDS dest (wave-uniform base + lane*16),
    // source column pre-swizzled so that a swizzled READ returns the right data.
    auto stage = [&](int b, int k0) {
        #pragma unroll
        for (int it = 0; it < 2; ++it) {
            int e = (it * 256 + tid) * 8;          // linear element slot in 128x32 tile
            int r = e >> 5, kks = e & 31;
            int kk = kks ^ (((r >> 1) & 3) << 3);  // involution: source col for this slot
            gld16(Abase + (size_t)r * K + k0 + kk, &As[b][0][0] + e);
            gld16(Bbase + (size_t)r * K + k0 + kk, &Bs[b][0][0] + e);
        }
    };

    int nt = K >> 5;
    stage(0, 0);
    int cur = 0;
    for (int t = 0; t < nt; ++t) {
        if (t + 1 < nt) {
            stage(cur ^ 1, (t + 1) << 5);
            asm volatile("s_waitcnt vmcnt(4)" ::: "memory");   // own loads for tile t done; t+1 stays in flight
        } else {
            asm volatile("s_waitcnt vmcnt(0)" ::: "memory");
        }
        __builtin_amdgcn_s_barrier();                          // all waves' tile-t writes visible
        __builtin_amdgcn_sched_barrier(0);
        bf16x8 af[4], bfr[4];
        int col = 8 * l4;
        #pragma unroll
        for (int mf = 0; mf < 4; ++mf) {
            int row = wm + mf * 16 + l15;
            af[mf] = *(const bf16x8*)(&As[cur][0][0] + row * BK + (col ^ (((row >> 1) & 3) << 3)));
        }
        #pragma unroll
        for (int nf = 0; nf < 4; ++nf) {
            int row = wn + nf * 16 + l15;
            bfr[nf] = *(const bf16x8*)(&Bs[cur][0][0] + row * BK + (col ^ (((row >> 1) & 3) << 3)));
        }
        #pragma unroll
        for (int mf = 0; mf < 4; ++mf)
            #pragma unroll
            for (int nf = 0; nf < 4; ++nf)
                acc[mf][nf] = __builtin_amdgcn_mfma_f32_16x16x32_bf16(af[mf], bfr[nf], acc[mf][nf], 0, 0, 0);
        __builtin_amdgcn_s_barrier();                          // reads of buf[cur] done before next overwrite
        cur ^= 1;
    }

    #pragma unroll
    for (int mf = 0; mf < 4; ++mf)
      #pragma unroll
      for (int nf = 0; nf < 4; ++nf)
        #pragma unroll
        for (int r = 0; r < 4; ++r) {
            int row = bm + wm + mf * 16 + l4 * 4 + r;
            int col = bn + wn + nf * 16 + l15;
            float v = acc[mf][nf][r] + bias[col];
            if constexpr (EPI == 0) {
                int bw_ = row >> 6, n_ = row & 63;
                if (col < 256) {
                    float q = v * 0.17677669529663687f;   // * hd^-0.5 (after bias, matching ref)
                    int h = col >> 5, d = col & 31;
                    qb[(((size_t)bw_ * 8 + h) * 64 + n_) * 32 + d] = (bf16)q;
                } else if (col < 512) {
                    int c2 = col - 256; int h = c2 >> 5, d = c2 & 31;
                    kb[(((size_t)bw_ * 8 + h) * 64 + n_) * 32 + d] = (bf16)v;
                } else {
                    int c2 = col - 512; int h = c2 >> 5, d = c2 & 31;
                    vtb[(((size_t)bw_ * 8 + h) * 32 + d) * 64 + n_] = (bf16)v;  // V transposed [hd][n]
                }
            } else if constexpr (EPI == 1) {
                int bw_ = row >> 6, n_ = row & 63;
                int b = bw_ >> 8, w = bw_ & 255;
                int wh = w >> 4, ww = w & 15;
                int ii = n_ >> 3, jj = n_ & 7;
                int ph = (wh * 8 + ii + 4) & 127, pw = (ww * 8 + jj + 4) & 127;
                size_t gidx = ((size_t)(b * LTOK + ph * 128 + pw)) * CDIM + col;
                outf[gidx] = add_f32[gidx] + v;
            } else if constexpr (EPI == 2) {
                outb[(size_t)row * N + col] = (bf16)gelu_exact(v);
            } else {
                size_t gidx = (size_t)(row0 + row) * N + col;
                outf[gidx] = v + add_f32[gidx];     // in-place residual add (same thread)
            }
        }
}

// ---------------- attention: one wave per (window, head) ----------------
__global__ __launch_bounds__(256) void attn_kernel(
    const bf16* __restrict__ qb, const bf16* __restrict__ kb, const bf16* __restrict__ vtb,
    const float* __restrict__ btab, bf16* __restrict__ ao)
{
    __shared__ bf16 P[4][64][72];
    int wid = threadIdx.x >> 6, lane = threadIdx.x & 63;
    int pair = blockIdx.x * 4 + wid;          // 8192 pairs
    int bw = pair >> 3, h = pair & 7;
    int l15 = lane & 15, l4 = lane >> 4;
    const bf16* Q  = qb  + ((size_t)bw * 8 + h) * 64 * 32;
    const bf16* Kp = kb  + ((size_t)bw * 8 + h) * 64 * 32;
    const bf16* Vt = vtb + ((size_t)bw * 8 + h) * 32 * 64;

    bf16x8 aq[4], bk[4];
    #pragma unroll
    for (int mf = 0; mf < 4; ++mf) aq[mf] = *(const bf16x8*)(Q  + (mf * 16 + l15) * 32 + 8 * l4);
    #pragma unroll
    for (int nf = 0; nf < 4; ++nf) bk[nf] = *(const bf16x8*)(Kp + (nf * 16 + l15) * 32 + 8 * l4);
    f32x4 s[4][4] = {};
    #pragma unroll
    for (int mf = 0; mf < 4; ++mf)
        #pragma unroll
        for (int nf = 0; nf < 4; ++nf)
            s[mf][nf] = __builtin_amdgcn_mfma_f32_16x16x32_bf16(aq[mf], bk[nf], s[mf][nf], 0, 0, 0);

    int w = bw & 255, wh = w >> 4, ww = w & 15;
    int ccode[4];
    #pragma unroll
    for (int nf = 0; nf < 4; ++nf) {
        int m_ = nf * 16 + l15;
        int hc = (wh == 15) ? (((m_ >> 3) < 4) ? 1 : 2) : 0;
        int wc = (ww == 15) ? (((m_ & 7) < 4) ? 1 : 2) : 0;
        ccode[nf] = hc * 3 + wc;
    }
    float rs[4][4];
    #pragma unroll
    for (int mf = 0; mf < 4; ++mf) {
        #pragma unroll
        for (int r = 0; r < 4; ++r) {
            int n_ = mf * 16 + l4 * 4 + r;
            int hc = (wh == 15) ? (((n_ >> 3) < 4) ? 1 : 2) : 0;
            int wc = (ww == 15) ? (((n_ & 7) < 4) ? 1 : 2) : 0;
            int rcode = hc * 3 + wc;
            float sv[4];
            float mx = -1e30f;
            #pragma unroll
            for (int nf = 0; nf < 4; ++nf) {
                int m_ = nf * 16 + l15;
                float t = s[mf][nf][r] + btab[(h * 64 + n_) * 64 + m_];
                if (ccode[nf] != rcode) t -= 100.0f;
                sv[nf] = t;
                mx = fmaxf(mx, t);
            }
            #pragma unroll
            for (int msk = 1; msk < 16; msk <<= 1) mx = fmaxf(mx, __shfl_xor(mx, msk));
            float sum = 0.0f;
            #pragma unroll
            for (int nf = 0; nf < 4; ++nf) { sv[nf] = __expf(sv[nf] - mx); sum += sv[nf]; }
            #pragma unroll
            for (int msk = 1; msk < 16; msk <<= 1) sum += __shfl_xor(sum, msk);
            rs[mf][r] = sum;
            #pragma unroll
            for (int nf = 0; nf < 4; ++nf) P[wid][n_][nf * 16 + l15] = (bf16)sv[nf];
        }
    }
    __syncthreads();

    f32x4 o[4][2] = {};
    #pragma unroll
    for (int kf = 0; kf < 2; ++kf) {
        bf16x8 bv[2];
        #pragma unroll
        for (int nf = 0; nf < 2; ++nf) bv[nf] = *(const bf16x8*)(Vt + (nf * 16 + l15) * 64 + kf * 32 + 8 * l4);
        #pragma unroll
        for (int mf = 0; mf < 4; ++mf) {
            bf16x8 pa = *(const bf16x8*)(&P[wid][mf * 16 + l15][kf * 32 + 8 * l4]);
            #pragma unroll
            for (int nf = 0; nf < 2; ++nf)
                o[mf][nf] = __builtin_amdgcn_mfma_f32_16x16x32_bf16(pa, bv[nf], o[mf][nf], 0, 0, 0);
        }
    }
    #pragma unroll
    for (int mf = 0; mf < 4; ++mf)
      #pragma unroll
      for (int nf = 0; nf < 2; ++nf)
        #pragma unroll
        for (int r = 0; r < 4; ++r) {
            int n_ = mf * 16 + l4 * 4 + r;
            int d = nf * 16 + l15;
            float val = o[mf][nf][r] / rs[mf][r];
            ao[((size_t)bw * 64 + n_) * CDIM + h * 32 + d] = (bf16)val;
        }
}

// ---------------- depthwise 3x3 conv + gelu (chunk-local h1/h2, global coords from pix0) ----------------
__global__ void dwconv_kernel(const bf16* __restrict__ h1, const float* __restrict__ dww,
                              const float* __restrict__ dwb, bf16* __restrict__ h2, int pix0) {
    int gid = blockIdx.x * 256 + threadIdx.x;   // npix*128
    int c8 = (gid & 127) * 8;
    int lpix = gid >> 7;
    int pix = pix0 + lpix;
    int b = pix >> 14, p = pix & 16383;
    int ph = p >> 7, pw = p & 127;
    float acc[8];
    #pragma unroll
    for (int j = 0; j < 8; ++j) acc[j] = dwb[c8 + j];
    #pragma unroll
    for (int dy = -1; dy <= 1; ++dy) {
        int y = ph + dy;
        if ((unsigned)y >= 128u) continue;
        #pragma unroll
        for (int dx = -1; dx <= 1; ++dx) {
            int x = pw + dx;
            if ((unsigned)x >= 128u) continue;
            int ln_ = b * LTOK + y * 128 + x - pix0;    // chunk-local neighbor pixel
            bf16x8 v = *(const bf16x8*)(h1 + (size_t)ln_ * HIDDEN + c8);
            const float* wp = dww + ((dy + 1) * 3 + (dx + 1)) * HIDDEN + c8;
            #pragma unroll
            for (int j = 0; j < 8; ++j) acc[j] += (float)v[j] * wp[j];
        }
    }
    bf16x8 o;
    #pragma unroll
    for (int j = 0; j < 8; ++j) o[j] = (bf16)gelu_exact(acc[j]);
    *(bf16x8*)(h2 + (size_t)lpix * HIDDEN + c8) = o;
}

// ---------------- launch ----------------
extern "C" void kernel_launch(void* const* d_in, const int* in_sizes, int n_in,
                              void* d_out, int out_size, void* d_ws, size_t ws_size,
                              hipStream_t stream) {
    const float* x    = (const float*)d_in[0];
    const float* g1   = (const float*)d_in[1];
    const float* be1  = (const float*)d_in[2];
    const float* wq   = (const float*)d_in[3];
    const float* bq   = (const float*)d_in[4];
    const float* wkv  = (const float*)d_in[5];
    const float* bkv  = (const float*)d_in[6];
    const float* rpb  = (const float*)d_in[7];
    const float* wo   = (const float*)d_in[8];
    const float* bo   = (const float*)d_in[9];
    const float* g2   = (const float*)d_in[10];
    const float* be2  = (const float*)d_in[11];
    const float* w1   = (const float*)d_in[12];
    const float* bl1  = (const float*)d_in[13];
    const float* dww  = (const float*)d_in[14];
    const float* dwb  = (const float*)d_in[15];
    const float* w2   = (const float*)d_in[16];
    const float* bl2  = (const float*)d_in[17];
    float* out = (float*)d_out;

    // ---- workspace layout (total ~162 MiB) ----
    char* ws = (char*)d_ws;
    bf16*  wqkvt  = (bf16*)(ws + 0);                      // 768*256*2      = 393216
    float* biasq  = (float*)(ws + 393216);                // 768*4          = 3072
    bf16*  wot    = (bf16*)(ws + 396288);                 // 256*256*2      = 131072
    bf16*  w1t    = (bf16*)(ws + 527360);                 // 1024*256*2     = 524288
    bf16*  w2t    = (bf16*)(ws + 1051648);                // 256*1024*2     = 524288
    float* btab   = (float*)(ws + 1575936);               // 8*64*64*4      = 131072
    char*  R1     = ws + 1707008;                         // 96 MiB region
    char*  R2     = ws + 1707008 + 100663296;             // 64 MiB region   (end ~162 MiB)

    bf16*  qb   = (bf16*)(R1 + 0);                        // 32 MiB
    bf16*  kb   = (bf16*)(R1 + 33554432);                 // 32 MiB
    bf16*  vtb  = (bf16*)(R1 + 67108864);                 // 32 MiB
    bf16*  yln  = (bf16*)(R1 + 0);                        // over qb (dead after attn)
    bf16*  h2c  = (bf16*)(R1 + 33554432);                 // 64 MiB chunk, over kb+vtb (dead)

    bf16*  ao   = (bf16*)(R2 + 0);                        // 32 MiB
    bf16*  h1c  = (bf16*)(R2 + 0);                        // 64 MiB chunk, over ao (dead after proj)

    bf16*  xw   = (bf16*)d_out;                           // 32 MiB inside d_out (dead before proj)
    float* x2   = (float*)d_out;                          // f32 residual stream lives in d_out

    // prep
    prep_qkvw<<<768, 256, 0, stream>>>(wq, bq, wkv, bkv, wqkvt, biasq);
    prep_wt<<<256, 256, 0, stream>>>(wo, wot, 256, 256);
    prep_wt<<<1024, 256, 0, stream>>>(w1, w1t, 256, 1024);
    prep_wt<<<1024, 256, 0, stream>>>(w2, w2t, 1024, 256);
    prep_btab<<<128, 256, 0, stream>>>(rpb, btab);

    // LN1 + shift + window partition -> xw (in d_out)
    ln1_winpart<<<16384, 256, 0, stream>>>(x, g1, be1, xw);

    // QKV
    gemm_bt<0><<<dim3(512, 6), 256, 0, stream>>>(xw, wqkvt, biasq, TOK_TOTAL, 768, 256, 0,
                                                 nullptr, nullptr, nullptr, qb, kb, vtb);
    // attention
    attn_kernel<<<2048, 256, 0, stream>>>(qb, kb, vtb, btab, ao);

    // proj + win_rev + roll + residual -> x2 (f32, in d_out; xw dead)
    gemm_bt<1><<<dim3(512, 2), 256, 0, stream>>>(ao, wot, bo, TOK_TOTAL, 256, 256, 0,
                                                 nullptr, x2, x, nullptr, nullptr, nullptr);
    // LN2 (reads d_out) -> yln
    ln2_kernel<<<16384, 256, 0, stream>>>(x2, g2, be2, yln);

    // MLP1+gelu -> conv+gelu -> MLP2+residual, chunked by 2 batches (exact: no cross-batch halo)
    for (int c = 0; c < 2; ++c) {
        int pix0 = c * 32768;
        gemm_bt<2><<<dim3(256, 8), 256, 0, stream>>>(yln + (size_t)pix0 * CDIM, w1t, bl1,
                                                     32768, HIDDEN, 256, 0,
                                                     h1c, nullptr, nullptr, nullptr, nullptr, nullptr);
        dwconv_kernel<<<16384, 256, 0, stream>>>(h1c, dww, dwb, h2c, pix0);
        gemm_bt<3><<<dim3(256, 2), 256, 0, stream>>>(h2c, w2t, bl2, 32768, 256, HIDDEN, pix0,
                                                     nullptr, x2, x2, nullptr, nullptr, nullptr);
    }
}